// Round 6
// baseline (60.558 us; speedup 1.0000x reference)
//
#include <hip/hip_runtime.h>
#include <cmath>
#include <stdint.h>

#define MARGIN 0.1f
#define EPS 1e-5f

#define TPB    256      // 4 waves
#define BLOCKS 1024     // 256 rows/block at N=262144
#define TROWS  16       // rows per tile
#define NTILES 16       // 256 / TROWS
#define NBUF   3        // triple buffer

typedef float vf4 __attribute__((ext_vector_type(4)));

// global -> LDS direct DMA, 16B per lane (1 KB per wave-instruction).
// LDS dest is wave-uniform base + lane*16; global src is per-lane.
#define GLD(g, l)                                                            \
    __builtin_amdgcn_global_load_lds(                                        \
        (const __attribute__((address_space(1))) uint32_t*)(uintptr_t)(const void*)(g), \
        (__attribute__((address_space(3))) uint32_t*)(uintptr_t)(void*)(l),  \
        16, 0, 0)

// Deep-pipelined LDS-staged kernel (T3/T4 pattern): per tile each wave issues
// 3 fire-and-forget global_load_lds ops (o-rows, t-rows, gathered n-rows);
// counted s_waitcnt vmcnt(6) + raw s_barrier keep 3 tiles (9 KB/wave) in
// flight across barriers. Requires n == BLOCKS*TROWS*NTILES (262144).
__global__ __launch_bounds__(TPB, 4) void hinge_partial_kernel(
    const float* __restrict__ outp,   // [N,64] "output" (v)
    const float* __restrict__ tgt,    // [N,64] "target" (u)
    const int*   __restrict__ nidx,   // [N] negative indices
    float* __restrict__ partials,     // [BLOCKS]
    int n)
{
    __shared__ float sO[NBUF][TROWS][64];   // 12 KB per buffer, 36 KB total
    __shared__ float sT[NBUF][TROWS][64];
    __shared__ float sN[NBUF][TROWS][64];

    const int tid  = threadIdx.x;
    const int lane = tid & 63;
    const int w    = tid >> 6;                    // wave id 0..3
    const int base = blockIdx.x * (TROWS * NTILES);

    // Preload ALL gather indices this wave needs (1 per tile per lane:
    // lanes 0-15 stage tile-row w*4+0, 16-31 -> +1, ...). Fully unrolled so
    // jt[] stays in registers (rule #20).
    int jt[NTILES];
    #pragma unroll
    for (int T = 0; T < NTILES; ++T)
        jt[T] = nidx[base + T * TROWS + (w << 2) + (lane >> 4)];

    // Drain the index loads once so every outstanding VMEM op below is a
    // global_load_lds and the manual vmcnt counts are exact.
    asm volatile("s_waitcnt vmcnt(0)" ::: "memory");

    // wave w stages tile rows [w*4, w*4+4) of each array: 1 KB each.
#define STAGE(T, B) do {                                                      \
        const size_t r0 = (size_t)(base + (T) * TROWS + (w << 2));            \
        GLD(outp + (r0 << 6)            + lane * 4,        &sO[B][w << 2][0]);\
        GLD(tgt  + (r0 << 6)            + lane * 4,        &sT[B][w << 2][0]);\
        GLD(tgt  + ((size_t)jt[T] << 6) + (lane & 15) * 4, &sN[B][w << 2][0]);\
    } while (0)

    const int rr  = tid >> 4;        // tile row 0..15 (16 lanes per row)
    const int cc  = tid & 15;
    const int cc4 = cc * 4;
    float loss = 0.0f;

#define COMPUTE(B) do {                                                       \
        const vf4 ov = *(const vf4*)&sO[B][rr][cc4];                          \
        const vf4 tv = *(const vf4*)&sT[B][rr][cc4];                          \
        const vf4 nv = *(const vf4*)&sN[B][rr][cc4];                          \
        float d, sp = 0.f, sn = 0.f, un, vn, wn;                              \
        d = tv.x - ov.x; sp += d * d;  d = tv.y - ov.y; sp += d * d;          \
        d = tv.z - ov.z; sp += d * d;  d = tv.w - ov.w; sp += d * d;          \
        d = nv.x - ov.x; sn += d * d;  d = nv.y - ov.y; sn += d * d;          \
        d = nv.z - ov.z; sn += d * d;  d = nv.w - ov.w; sn += d * d;          \
        un = tv.x * tv.x + tv.y * tv.y + tv.z * tv.z + tv.w * tv.w;           \
        vn = ov.x * ov.x + ov.y * ov.y + ov.z * ov.z + ov.w * ov.w;           \
        wn = nv.x * nv.x + nv.y * nv.y + nv.z * nv.z + nv.w * nv.w;           \
        _Pragma("unroll")                                                     \
        for (int m = 1; m <= 8; m <<= 1) {                                    \
            sp += __shfl_xor(sp, m, 64); sn += __shfl_xor(sn, m, 64);         \
            un += __shfl_xor(un, m, 64); vn += __shfl_xor(vn, m, 64);         \
            wn += __shfl_xor(wn, m, 64);                                      \
        }                                                                     \
        if (cc == 0) {                                                        \
            const float xp = 1.0f + 2.0f * sp / ((1.0f - un) * (1.0f - vn));  \
            const float xn = 1.0f + 2.0f * sn / ((1.0f - wn) * (1.0f - vn));  \
            loss += fmaxf(MARGIN + acoshf(fmaxf(xp, 1.0f + EPS))              \
                                 - acoshf(fmaxf(xn, 1.0f + EPS)), 0.0f);      \
        }                                                                     \
    } while (0)

    STAGE(0, 0);
    STAGE(1, 1);
    STAGE(2, 2);

    #pragma unroll
    for (int t = 0; t < NTILES; ++t) {
        // wait for tile t's DMA (3 ops/wave/tile; up to 2 newer tiles stay
        // in flight). Peeled counts for the drain tail.
        if (t <= NTILES - 3)      { asm volatile("s_waitcnt vmcnt(6)" ::: "memory"); }
        else if (t == NTILES - 2) { asm volatile("s_waitcnt vmcnt(3)" ::: "memory"); }
        else                      { asm volatile("s_waitcnt vmcnt(0)" ::: "memory"); }
        __builtin_amdgcn_s_barrier();            // raw barrier: no vmcnt(0) drain
        __builtin_amdgcn_sched_barrier(0);

        COMPUTE(t % 3);

        __builtin_amdgcn_s_barrier();            // all waves done reading buf
        __builtin_amdgcn_sched_barrier(0);
        if (t + 3 < NTILES) STAGE(t + 3, (t + 3) % 3);
    }

#undef STAGE
#undef COMPUTE

    // wave(64) shuffle reduce of per-thread loss
    #pragma unroll
    for (int off = 32; off > 0; off >>= 1)
        loss += __shfl_down(loss, off, 64);

    __shared__ float ws[4];
    if (lane == 0) ws[w] = loss;
    __syncthreads();
    if (tid == 0)
        partials[blockIdx.x] = ws[0] + ws[1] + ws[2] + ws[3];
}

// Stage 2: deterministic single-block reduction of block partials -> mean.
__global__ __launch_bounds__(256) void hinge_final_kernel(
    const float* __restrict__ partials, float* __restrict__ out,
    int nparts, float inv_n)
{
    float s = 0.0f;
    for (int i = threadIdx.x; i < nparts; i += 256)
        s += partials[i];

    #pragma unroll
    for (int off = 32; off > 0; off >>= 1)
        s += __shfl_down(s, off, 64);

    __shared__ float ws[4];
    const int lane = threadIdx.x & 63;
    const int wid  = threadIdx.x >> 6;
    if (lane == 0) ws[wid] = s;
    __syncthreads();
    if (threadIdx.x == 0)
        out[0] = (ws[0] + ws[1] + ws[2] + ws[3]) * inv_n;
}

extern "C" void kernel_launch(void* const* d_in, const int* in_sizes, int n_in,
                              void* d_out, int out_size, void* d_ws, size_t ws_size,
                              hipStream_t stream) {
    const float* outp = (const float*)d_in[0];  // "output" [N,64]
    const float* tgt  = (const float*)d_in[1];  // "target" [N,64]
    const int*   nidx = (const int*)d_in[2];    // neg_idx [N]
    float* out = (float*)d_out;
    float* partials = (float*)d_ws;

    const int n = in_sizes[2];                  // N rows (262144)

    hinge_partial_kernel<<<BLOCKS, TPB, 0, stream>>>(outp, tgt, nidx, partials, n);
    hinge_final_kernel<<<1, 256, 0, stream>>>(partials, out, BLOCKS, 1.0f / (float)n);
}

// Round 7
// 37.858 us; speedup vs baseline: 1.5996x; 1.5996x over previous
//
#include <hip/hip_runtime.h>
#include <cmath>
#include <stdint.h>

#define MARGIN 0.1f
#define EPS 1e-5f

#define TPB    256
#define BLOCKS 1024
#define RPT    4     // rows per 4-lane group (grid-strided)

typedef float vf4 __attribute__((ext_vector_type(4)));

// Forced-in-flight loads: explicit "=v" destinations make the allocator keep
// every result register live; hand-counted vmcnt replaces compiler waits.
#define LOAD4(dst, ptr, OFF)                                              \
    asm volatile("global_load_dwordx4 %0, %1, off offset:" #OFF           \
                 : "=v"(dst) : "v"(ptr) : "memory")
#define LOADI(dst, ptr)                                                   \
    asm volatile("global_load_dword %0, %1, off"                          \
                 : "=v"(dst) : "v"(ptr) : "memory")
// rule #18: sched_barrier after an asm waitcnt, else hipcc hoists the
// register-only FP consumers above the wait.
#define WAITV(N) do {                                                     \
        asm volatile("s_waitcnt vmcnt(" #N ")" ::: "memory");             \
        __builtin_amdgcn_sched_barrier(0);                                \
    } while (0)

// Pipeline (ops in program order; vmcnt arg = allowed outstanding):
//   idx0..3                  |  4 out
//   oA,tA (row0)             | 12
//   vmcnt(8)   -> idx done
//   nA (row0)                | <=12
//   oB,tB,nB (row1)          | <=24
//   vmcnt(12)  -> row0 done  -> COMPUTE(row0)
//   oA,tA,nA (row2)          | <=24
//   vmcnt(12)  -> row1 done  -> COMPUTE(row1)
//   oB,tB,nB (row3)          | <=24
//   vmcnt(12)  -> row2 done  -> COMPUTE(row2)
//   vmcnt(0)   -> row3 done  -> COMPUTE(row3)
__global__ __launch_bounds__(TPB, 4) void hinge_partial_kernel(
    const float* __restrict__ outp,   // [N,64] "output" (v)
    const float* __restrict__ tgt,    // [N,64] "target" (u)
    const int*   __restrict__ nidx,   // [N] negative indices
    float* __restrict__ partials,     // [BLOCKS]
    int n)
{
    const int g   = blockIdx.x * TPB + threadIdx.x;
    const int grp = g >> 2;
    const int sub = g & 3;                 // lane's float4 slot within the row
    const int G   = (BLOCKS * TPB) >> 2;   // groups in grid

    int  rows[RPT];
    bool valid[RPT];
    #pragma unroll
    for (int p = 0; p < RPT; ++p) {
        const int r = grp + p * G;
        valid[p] = (r < n);
        rows[p]  = valid[p] ? r : 0;
    }

    int j0, j1, j2, j3;
    LOADI(j0, nidx + rows[0]);
    LOADI(j1, nidx + rows[1]);
    LOADI(j2, nidx + rows[2]);
    LOADI(j3, nidx + rows[3]);

    vf4 oA[4], tA[4], nA[4];
    vf4 oB[4], tB[4], nB[4];

    // lane handles float4 slots {sub, sub+4, sub+8, sub+12}: byte off sub*16 + k*64
#define LOADOT(BO, BT, P) do {                                            \
        const float* o_ = outp + ((size_t)rows[P] << 6) + sub * 4;        \
        const float* t_ = tgt  + ((size_t)rows[P] << 6) + sub * 4;        \
        LOAD4(BO[0], o_, 0);   LOAD4(BO[1], o_, 64);                      \
        LOAD4(BO[2], o_, 128); LOAD4(BO[3], o_, 192);                     \
        LOAD4(BT[0], t_, 0);   LOAD4(BT[1], t_, 64);                      \
        LOAD4(BT[2], t_, 128); LOAD4(BT[3], t_, 192);                     \
    } while (0)

#define LOADN(BN, J) do {                                                 \
        const float* n_ = tgt + ((size_t)(uint32_t)(J) << 6) + sub * 4;   \
        LOAD4(BN[0], n_, 0);   LOAD4(BN[1], n_, 64);                      \
        LOAD4(BN[2], n_, 128); LOAD4(BN[3], n_, 192);                     \
    } while (0)

    float loss = 0.0f;

#define COMPUTE(BO, BT, BN, P) do {                                       \
        float sp = 0.f, sn = 0.f, un = 0.f, vn = 0.f, wn = 0.f;           \
        _Pragma("unroll")                                                 \
        for (int k = 0; k < 4; ++k) {                                     \
            const vf4 ov = BO[k], tv = BT[k], nv = BN[k];                 \
            float d;                                                      \
            d = tv.x - ov.x; sp += d * d;                                 \
            d = tv.y - ov.y; sp += d * d;                                 \
            d = tv.z - ov.z; sp += d * d;                                 \
            d = tv.w - ov.w; sp += d * d;                                 \
            d = nv.x - ov.x; sn += d * d;                                 \
            d = nv.y - ov.y; sn += d * d;                                 \
            d = nv.z - ov.z; sn += d * d;                                 \
            d = nv.w - ov.w; sn += d * d;                                 \
            un += tv.x * tv.x + tv.y * tv.y + tv.z * tv.z + tv.w * tv.w;  \
            vn += ov.x * ov.x + ov.y * ov.y + ov.z * ov.z + ov.w * ov.w;  \
            wn += nv.x * nv.x + nv.y * nv.y + nv.z * nv.z + nv.w * nv.w;  \
        }                                                                 \
        _Pragma("unroll")                                                 \
        for (int mask = 1; mask <= 2; mask <<= 1) {                       \
            sp += __shfl_xor(sp, mask, 64);                               \
            sn += __shfl_xor(sn, mask, 64);                               \
            un += __shfl_xor(un, mask, 64);                               \
            vn += __shfl_xor(vn, mask, 64);                               \
            wn += __shfl_xor(wn, mask, 64);                               \
        }                                                                 \
        if (sub == 0 && valid[P]) {                                       \
            const float xp = 1.0f + 2.0f * sp / ((1.0f - un) * (1.0f - vn)); \
            const float xn = 1.0f + 2.0f * sn / ((1.0f - wn) * (1.0f - vn)); \
            loss += fmaxf(MARGIN + acoshf(fmaxf(xp, 1.0f + EPS))          \
                                 - acoshf(fmaxf(xn, 1.0f + EPS)), 0.0f);  \
        }                                                                 \
    } while (0)

    LOADOT(oA, tA, 0);          // 12 outstanding (4 idx + 8)
    WAITV(8);                   // idx loads complete
    LOADN(nA, j0);              // row0 gather
    LOADOT(oB, tB, 1);
    LOADN(nB, j1);              // <=24 outstanding

    WAITV(12);                  // row0 (oA,tA,nA) complete
    COMPUTE(oA, tA, nA, 0);
    LOADOT(oA, tA, 2);
    LOADN(nA, j2);

    WAITV(12);                  // row1 complete
    COMPUTE(oB, tB, nB, 1);
    LOADOT(oB, tB, 3);
    LOADN(nB, j3);

    WAITV(12);                  // row2 complete
    COMPUTE(oA, tA, nA, 2);

    WAITV(0);                   // row3 complete
    COMPUTE(oB, tB, nB, 3);

#undef LOADOT
#undef LOADN
#undef COMPUTE

    // wave(64) shuffle reduce
    #pragma unroll
    for (int off = 32; off > 0; off >>= 1)
        loss += __shfl_down(loss, off, 64);

    __shared__ float ws[4];
    const int lane = threadIdx.x & 63;
    const int wid  = threadIdx.x >> 6;
    if (lane == 0) ws[wid] = loss;
    __syncthreads();
    if (threadIdx.x == 0)
        partials[blockIdx.x] = ws[0] + ws[1] + ws[2] + ws[3];
}

// Stage 2: deterministic single-block reduction of block partials -> mean.
__global__ __launch_bounds__(256) void hinge_final_kernel(
    const float* __restrict__ partials, float* __restrict__ out,
    int nparts, float inv_n)
{
    float s = 0.0f;
    for (int i = threadIdx.x; i < nparts; i += 256)
        s += partials[i];

    #pragma unroll
    for (int off = 32; off > 0; off >>= 1)
        s += __shfl_down(s, off, 64);

    __shared__ float ws[4];
    const int lane = threadIdx.x & 63;
    const int wid  = threadIdx.x >> 6;
    if (lane == 0) ws[wid] = s;
    __syncthreads();
    if (threadIdx.x == 0)
        out[0] = (ws[0] + ws[1] + ws[2] + ws[3]) * inv_n;
}

extern "C" void kernel_launch(void* const* d_in, const int* in_sizes, int n_in,
                              void* d_out, int out_size, void* d_ws, size_t ws_size,
                              hipStream_t stream) {
    const float* outp = (const float*)d_in[0];  // "output" [N,64]
    const float* tgt  = (const float*)d_in[1];  // "target" [N,64]
    const int*   nidx = (const int*)d_in[2];    // neg_idx [N]
    float* out = (float*)d_out;
    float* partials = (float*)d_ws;

    const int n = in_sizes[2];                  // N rows

    hinge_partial_kernel<<<BLOCKS, TPB, 0, stream>>>(outp, tgt, nidx, partials, n);
    hinge_final_kernel<<<1, 256, 0, stream>>>(partials, out, BLOCKS, 1.0f / (float)n);
}